// Round 2
// 1524.987 us; speedup vs baseline: 1.1823x; 1.1823x over previous
//
#include <hip/hip_runtime.h>
#include <math.h>

// Problem constants (from reference)
static const int N0 = 1000000, N1 = 100000, N2 = 10000, N3 = 1024;
static const int E0 = 1500000, E1 = 150000, E2 = 15360;
static const int D = 128, H = 512;

typedef unsigned short u16;
typedef __attribute__((ext_vector_type(8))) short bf16x8;   // 8 bf16 = 4 VGPRs
typedef __attribute__((ext_vector_type(4))) float f32x4;
typedef __attribute__((ext_vector_type(4))) unsigned short us4;
typedef __attribute__((ext_vector_type(4))) int i32x4;

// ---------------------------------------------------------------------------
// Edge-count histogram: cnt[dst[e]] += 1 (int atomics, tiny)
// ---------------------------------------------------------------------------
__global__ void count_kernel(const int* __restrict__ dst, int* __restrict__ cnt, int E) {
    int e = blockIdx.x * blockDim.x + threadIdx.x;
    if (e < E) atomicAdd(cnt + dst[e], 1);
}

// ---------------------------------------------------------------------------
// Single-block exclusive scan: offs[i] = sum(cnt[0..i)), offs[N] = E
// ---------------------------------------------------------------------------
__global__ __launch_bounds__(1024)
void scan_kernel(const int* __restrict__ cnt, int* __restrict__ offs, int N, int E) {
    __shared__ int part[1024];
    int t = threadIdx.x;
    int per = (N + 1023) >> 10;
    int beg = t * per, end = min(beg + per, N);
    int s = 0;
    for (int i = beg; i < end; ++i) s += cnt[i];
    part[t] = s;
    __syncthreads();
    for (int off = 1; off < 1024; off <<= 1) {
        int v = (t >= off) ? part[t - off] : 0;
        __syncthreads();
        part[t] += v;
        __syncthreads();
    }
    int run = (t == 0) ? 0 : part[t - 1];
    for (int i = beg; i < end; ++i) { offs[i] = run; run += cnt[i]; }
    if (t == 0) offs[N] = E;
}

// ---------------------------------------------------------------------------
// Bucket fill: sorted[offs[dst[e]] + cursor++] = src[e]
// ---------------------------------------------------------------------------
__global__ void fill_kernel(const int* __restrict__ dst, const int* __restrict__ src,
                            const int* __restrict__ offs, int* __restrict__ cur,
                            int* __restrict__ sorted, int E) {
    int e = blockIdx.x * blockDim.x + threadIdx.x;
    if (e < E) {
        int d = dst[e];
        int p = offs[d] + atomicAdd(cur + d, 1);
        sorted[p] = src[e];
    }
}

// ---------------------------------------------------------------------------
// Gather-mean, D=128: one wave per dst node; lane holds float2 of the row.
// ---------------------------------------------------------------------------
__global__ __launch_bounds__(256)
void gather_mean_128(const float* __restrict__ x, const int* __restrict__ offs,
                     const int* __restrict__ srt, float* __restrict__ agg, int Ntgt) {
    int wid = (int)((blockIdx.x * 256 + threadIdx.x) >> 6);
    int lane = threadIdx.x & 63;
    if (wid >= Ntgt) return;
    int beg = offs[wid], end = offs[wid + 1];
    float ax = 0.f, ay = 0.f;
    int e = beg;
    for (; e + 4 <= end; e += 4) {
        int s0 = srt[e], s1 = srt[e + 1], s2 = srt[e + 2], s3 = srt[e + 3];
        float2 v0 = ((const float2*)(x + (size_t)s0 * 128))[lane];
        float2 v1 = ((const float2*)(x + (size_t)s1 * 128))[lane];
        float2 v2 = ((const float2*)(x + (size_t)s2 * 128))[lane];
        float2 v3 = ((const float2*)(x + (size_t)s3 * 128))[lane];
        ax += v0.x + v1.x + v2.x + v3.x;
        ay += v0.y + v1.y + v2.y + v3.y;
    }
    for (; e < end; ++e) {
        int s = srt[e];
        float2 v = ((const float2*)(x + (size_t)s * 128))[lane];
        ax += v.x; ay += v.y;
    }
    float inv = 1.0f / (float)max(end - beg, 1);
    ((float2*)(agg + (size_t)wid * 128))[lane] = make_float2(ax * inv, ay * inv);
}

// ---------------------------------------------------------------------------
// Gather-mean, D=512: one wave per (node, half); lane holds float4 of 256-float half.
// ---------------------------------------------------------------------------
__global__ __launch_bounds__(256)
void gather_mean_512(const float* __restrict__ x, const int* __restrict__ offs,
                     const int* __restrict__ srt, float* __restrict__ agg, int Ntgt) {
    int gw = (int)((blockIdx.x * 256 + threadIdx.x) >> 6);
    int lane = threadIdx.x & 63;
    int node = gw >> 1, half = gw & 1;
    if (node >= Ntgt) return;
    int beg = offs[node], end = offs[node + 1];
    int co = half * 256 + lane * 4;
    float4 acc = make_float4(0.f, 0.f, 0.f, 0.f);
    int e = beg;
    for (; e + 4 <= end; e += 4) {
        int s0 = srt[e], s1 = srt[e + 1], s2 = srt[e + 2], s3 = srt[e + 3];
        float4 v0 = *(const float4*)(x + (size_t)s0 * 512 + co);
        float4 v1 = *(const float4*)(x + (size_t)s1 * 512 + co);
        float4 v2 = *(const float4*)(x + (size_t)s2 * 512 + co);
        float4 v3 = *(const float4*)(x + (size_t)s3 * 512 + co);
        acc.x += v0.x + v1.x + v2.x + v3.x;
        acc.y += v0.y + v1.y + v2.y + v3.y;
        acc.z += v0.z + v1.z + v2.z + v3.z;
        acc.w += v0.w + v1.w + v2.w + v3.w;
    }
    for (; e < end; ++e) {
        int s = srt[e];
        float4 v = *(const float4*)(x + (size_t)s * 512 + co);
        acc.x += v.x; acc.y += v.y; acc.z += v.z; acc.w += v.w;
    }
    float inv = 1.0f / (float)max(end - beg, 1);
    acc.x *= inv; acc.y *= inv; acc.z *= inv; acc.w *= inv;
    *(float4*)(agg + (size_t)node * 512 + co) = acc;
}

// ---------------------------------------------------------------------------
// Exact fp32 -> bf16 hi/lo split (truncation; v == hi + lo to ~2^-16 rel).
// Pure bit ops, returns by value (ext_vector elements can't bind to refs).
// ---------------------------------------------------------------------------
__device__ __forceinline__ u16 bhi(float v) {
    return (u16)(__float_as_uint(v) >> 16);
}
__device__ __forceinline__ u16 blo(float v) {
    float hf = __uint_as_float(__float_as_uint(v) & 0xFFFF0000u);
    return (u16)(__float_as_uint(v - hf) >> 16);
}

// ---------------------------------------------------------------------------
// Weight pre-transpose + split: W[K][N] fp32 -> bt hi plane [N][K] bf16,
// then lo plane [N][K] bf16 at bt + N*K. Tiny (<= 262K elems).
// ---------------------------------------------------------------------------
__global__ void wsplit_kernel(const float* __restrict__ W, u16* __restrict__ bt,
                              int K, int N) {
    int idx = blockIdx.x * 256 + threadIdx.x;
    if (idx >= K * N) return;
    int k = idx / N, n = idx - k * N;          // coalesced read along n
    float v = W[idx];
    bt[(size_t)n * K + k] = bhi(v);
    bt[(size_t)N * K + (size_t)n * K + k] = blo(v);
}

// ---------------------------------------------------------------------------
// Fused combine via split-bf16 MFMA:
//   out = act( A0 @ W0 + A1 @ W1 + bias )
// A0/A1: fp32 [M][K] (converted to hi/lo bf16 during LDS staging).
// Bt0/Bt1: pre-split weights, hi plane [N][K] bf16 + lo plane at +N*K.
// 128x128 block tile, 256 threads = 4 waves (2x2), wave tile 64x64 as
// 4x4 mfma_f32_16x16x32_bf16 fragments. 3 MFMA terms per fragment pair
// (hi*hi + hi*lo + lo*hi) => fp32-equivalent accuracy.
// ---------------------------------------------------------------------------
#define LDK 40   // padded k-stride in bf16 elems (32 + 8): 80B rows, 16B-aligned frags

template <bool GELU>
__global__ __launch_bounds__(256)
void combine_mfma(const float* __restrict__ A0, const float* __restrict__ A1,
                  const u16* __restrict__ Bt0, const u16* __restrict__ Bt1,
                  const float* __restrict__ bias, float* __restrict__ out,
                  int M, int K, int N) {
    __shared__ u16 As_hi[128][LDK];
    __shared__ u16 As_lo[128][LDK];
    __shared__ u16 Bs_hi[128][LDK];
    __shared__ u16 Bs_lo[128][LDK];

    int t = threadIdx.x;
    int lane = t & 63, wid = t >> 6;
    int wm = (wid >> 1) * 64, wn = (wid & 1) * 64;
    int m0 = blockIdx.y * 128, n0 = blockIdx.x * 128;

    // staging coords
    int ar = t >> 3;                 // A: row 0..31 per pass
    int akq = (t & 7) * 4;           // A: k quad {0,4,...,28}
    int bn = t >> 2;                 // B: n 0..63 per pass
    int bc = (t & 3) * 8;            // B: k oct {0,8,16,24}

    // fragment coords
    int fr = lane & 15, kg = lane >> 4;

    f32x4 acc[4][4] = {};

    for (int p = 0; p < 2; ++p) {
        const float* A  = p ? A1 : A0;
        const u16*   Bh = p ? Bt1 : Bt0;
        const u16*   Bl = Bh + (size_t)N * K;   // lo plane

        for (int k0 = 0; k0 < K; k0 += 32) {
            // ---- stage A tile 128x32: fp32 -> hi/lo bf16 in LDS ----
#pragma unroll
            for (int it = 0; it < 4; ++it) {
                int row = it * 32 + ar;
                int rg = m0 + row;
                f32x4 v = {0.f, 0.f, 0.f, 0.f};
                if (rg < M) v = *(const f32x4*)(A + (size_t)rg * K + k0 + akq);
                us4 hv = { bhi(v.x), bhi(v.y), bhi(v.z), bhi(v.w) };
                us4 lv = { blo(v.x), blo(v.y), blo(v.z), blo(v.w) };
                *(us4*)&As_hi[row][akq] = hv;
                *(us4*)&As_lo[row][akq] = lv;
            }
            // ---- stage B tile 128n x 32k from pre-split planes ----
#pragma unroll
            for (int it = 0; it < 2; ++it) {
                int nn = it * 64 + bn;
                size_t goff = (size_t)(n0 + nn) * K + k0 + bc;
                *(i32x4*)&Bs_hi[nn][bc] = *(const i32x4*)(Bh + goff);
                *(i32x4*)&Bs_lo[nn][bc] = *(const i32x4*)(Bl + goff);
            }
            __syncthreads();

            // ---- fragments + MFMA ----
            bf16x8 a_hi[4], a_lo[4], b_hi[4], b_lo[4];
#pragma unroll
            for (int i = 0; i < 4; ++i) {
                a_hi[i] = *(const bf16x8*)&As_hi[wm + i * 16 + fr][kg * 8];
                a_lo[i] = *(const bf16x8*)&As_lo[wm + i * 16 + fr][kg * 8];
                b_hi[i] = *(const bf16x8*)&Bs_hi[wn + i * 16 + fr][kg * 8];
                b_lo[i] = *(const bf16x8*)&Bs_lo[wn + i * 16 + fr][kg * 8];
            }
#pragma unroll
            for (int i = 0; i < 4; ++i)
#pragma unroll
                for (int j = 0; j < 4; ++j) {
                    acc[i][j] = __builtin_amdgcn_mfma_f32_16x16x32_bf16(
                        a_hi[i], b_hi[j], acc[i][j], 0, 0, 0);
                    acc[i][j] = __builtin_amdgcn_mfma_f32_16x16x32_bf16(
                        a_hi[i], b_lo[j], acc[i][j], 0, 0, 0);
                    acc[i][j] = __builtin_amdgcn_mfma_f32_16x16x32_bf16(
                        a_lo[i], b_hi[j], acc[i][j], 0, 0, 0);
                }
            __syncthreads();
        }
    }

    // ---- epilogue: C/D layout col=lane&15, row=(lane>>4)*4+reg (m89) ----
    int fq = lane >> 4;
#pragma unroll
    for (int i = 0; i < 4; ++i) {
        int rbase = m0 + wm + i * 16 + fq * 4;
#pragma unroll
        for (int j = 0; j < 4; ++j) {
            int c = n0 + wn + j * 16 + fr;
            float bv = bias[c];
#pragma unroll
            for (int r = 0; r < 4; ++r) {
                int row = rbase + r;
                if (row < M) {
                    float v = acc[i][j][r] + bv;
                    if (GELU) v = 0.5f * v * (1.0f + erff(v * 0.70710678118654752f));
                    out[(size_t)row * N + c] = v;
                }
            }
        }
    }
}

// ---------------------------------------------------------------------------
extern "C" void kernel_launch(void* const* d_in, const int* in_sizes, int n_in,
                              void* d_out, int out_size, void* d_ws, size_t ws_size,
                              hipStream_t stream) {
    const float* x       = (const float*)d_in[0];
    const int*   ei0_src = (const int*)d_in[1];
    const int*   ei0_dst = (const int*)d_in[2];
    const int*   ei1_src = (const int*)d_in[3];
    const int*   ei1_dst = (const int*)d_in[4];
    const int*   ei2_src = (const int*)d_in[5];
    const int*   ei2_dst = (const int*)d_in[6];
    const float* W_l0    = (const float*)d_in[7];
    const float* b_l0    = (const float*)d_in[8];
    const float* W_r0    = (const float*)d_in[9];
    const float* W_l1    = (const float*)d_in[10];
    const float* b_l1    = (const float*)d_in[11];
    const float* W_r1    = (const float*)d_in[12];
    const float* W_l2    = (const float*)d_in[13];
    const float* b_l2    = (const float*)d_in[14];
    const float* W_r2    = (const float*)d_in[15];
    float* out = (float*)d_out;
    float* ws  = (float*)d_ws;

    // ---- workspace layout (float slots) ----
    float* h1 = ws;
    int* offs0 = (int*)ws;                 // N1+1
    int* cnt0  = offs0 + (N1 + 1);         // N1
    int* cur0  = cnt0 + N1;                // N1
    int* srt0  = cur0 + N1;                // E0

    float* agg0 = h1 + (size_t)N1 * H;     // N1*D floats; reused after combine0:
    float* agg1 = agg0;                    //   N2*H
    float* h2   = agg1 + (size_t)N2 * H;   //   N2*H
    float* agg2 = h2 + (size_t)N2 * H;     //   N3*H

    u16* bt1l = (u16*)(agg2 + (size_t)N3 * H);      // W_l1 planes
    u16* bt1r = bt1l + (size_t)H * H * 2;           // W_r1
    u16* bt2l = bt1r + (size_t)H * H * 2;           // W_l2
    u16* bt2r = bt2l + (size_t)D * H * 2;           // W_r2

    u16* bt0l = (u16*)d_out;                        // layer-0 planes in d_out
    u16* bt0r = bt0l + (size_t)H * D * 2;

    int* tail  = (int*)(agg0 + (size_t)N1 * D);
    int* offs1 = tail;                     // N2+1
    int* cnt1  = offs1 + (N2 + 1);         // N2
    int* cur1  = cnt1 + N2;                // N2
    int* srt1  = cur1 + N2;                // E1
    int* offs2 = srt1 + E1;                // N3+1
    int* cnt2  = offs2 + (N3 + 1);         // N3
    int* cur2  = cnt2 + N3;                // N3
    int* srt2  = cur2 + N3;                // E2

    hipMemsetAsync(cnt0, 0, 2 * N1 * sizeof(int), stream);
    hipMemsetAsync(cnt1, 0, 2 * N2 * sizeof(int), stream);
    hipMemsetAsync(cnt2, 0, 2 * N3 * sizeof(int), stream);
    count_kernel<<<(E0 + 255) / 256, 256, 0, stream>>>(ei0_dst, cnt0, E0);
    count_kernel<<<(E1 + 255) / 256, 256, 0, stream>>>(ei1_dst, cnt1, E1);
    count_kernel<<<(E2 + 255) / 256, 256, 0, stream>>>(ei2_dst, cnt2, E2);
    scan_kernel<<<1, 1024, 0, stream>>>(cnt0, offs0, N1, E0);
    scan_kernel<<<1, 1024, 0, stream>>>(cnt1, offs1, N2, E1);
    scan_kernel<<<1, 1024, 0, stream>>>(cnt2, offs2, N3, E2);
    fill_kernel<<<(E0 + 255) / 256, 256, 0, stream>>>(ei0_dst, ei0_src, offs0, cur0, srt0, E0);
    fill_kernel<<<(E1 + 255) / 256, 256, 0, stream>>>(ei1_dst, ei1_src, offs1, cur1, srt1, E1);
    fill_kernel<<<(E2 + 255) / 256, 256, 0, stream>>>(ei2_dst, ei2_src, offs2, cur2, srt2, E2);

    // ---- layer-0 weight split (into d_out scratch) ----
    wsplit_kernel<<<(D * H + 255) / 256, 256, 0, stream>>>(W_l0, bt0l, D, H);
    wsplit_kernel<<<(D * H + 255) / 256, 256, 0, stream>>>(W_r0, bt0r, D, H);

    // ---- layer 0: x (N0,128) -> h1 (N1,512), GELU ----
    gather_mean_128<<<(N1 + 3) / 4, 256, 0, stream>>>(x, offs0, srt0, agg0, N1);
    combine_mfma<true><<<dim3(H / 128, (N1 + 127) / 128), 256, 0, stream>>>(
        agg0, x, bt0l, bt0r, b_l0, h1, N1, D, H);

    // ---- layer-1/2 weight splits (agg0 slack is now free) ----
    wsplit_kernel<<<(H * H + 255) / 256, 256, 0, stream>>>(W_l1, bt1l, H, H);
    wsplit_kernel<<<(H * H + 255) / 256, 256, 0, stream>>>(W_r1, bt1r, H, H);
    wsplit_kernel<<<(H * D + 255) / 256, 256, 0, stream>>>(W_l2, bt2l, H, D);
    wsplit_kernel<<<(H * D + 255) / 256, 256, 0, stream>>>(W_r2, bt2r, H, D);

    // ---- layer 1: h1 (N1,512) -> h2 (N2,512), GELU ----
    gather_mean_512<<<(2 * N2 + 3) / 4, 256, 0, stream>>>(h1, offs1, srt1, agg1, N2);
    combine_mfma<true><<<dim3(H / 128, (N2 + 127) / 128), 256, 0, stream>>>(
        agg1, h1, bt1l, bt1r, b_l1, h2, N2, H, H);

    // ---- layer 2: h2 (N2,512) -> out (N3,128), no act ----
    gather_mean_512<<<(2 * N3 + 3) / 4, 256, 0, stream>>>(h2, offs2, srt2, agg2, N3);
    combine_mfma<false><<<dim3(D / 128, (N3 + 127) / 128), 256, 0, stream>>>(
        agg2, h2, bt2l, bt2r, b_l2, out, N3, H, D);
}

// Round 3
// 1433.033 us; speedup vs baseline: 1.2581x; 1.0642x over previous
//
#include <hip/hip_runtime.h>
#include <math.h>

// Problem constants (from reference)
static const int N0 = 1000000, N1 = 100000, N2 = 10000, N3 = 1024;
static const int E0 = 1500000, E1 = 150000, E2 = 15360;
static const int D = 128, H = 512;

typedef unsigned short u16;
typedef unsigned int u32;
typedef __attribute__((ext_vector_type(8))) short bf16x8;   // 8 bf16 = 4 VGPRs
typedef __attribute__((ext_vector_type(4))) float f32x4;
typedef __attribute__((ext_vector_type(4))) unsigned short us4;
typedef __attribute__((ext_vector_type(4))) int i32x4;

// ---------------------------------------------------------------------------
// Exact fp32 -> bf16 hi/lo split (truncation; v == hi + lo to ~2^-16 rel).
// ---------------------------------------------------------------------------
__device__ __forceinline__ u16 bhi(float v) {
    return (u16)(__float_as_uint(v) >> 16);
}
__device__ __forceinline__ u16 blo(float v) {
    float hf = __uint_as_float(__float_as_uint(v) & 0xFFFF0000u);
    return (u16)(__float_as_uint(v - hf) >> 16);
}

// ---------------------------------------------------------------------------
// Edge-count histogram: cnt[dst[e]] += 1 (int atomics, tiny)
// ---------------------------------------------------------------------------
__global__ void count_kernel(const int* __restrict__ dst, int* __restrict__ cnt, int E) {
    int e = blockIdx.x * blockDim.x + threadIdx.x;
    if (e < E) atomicAdd(cnt + dst[e], 1);
}

// ---------------------------------------------------------------------------
// Single-block exclusive scan: offs[i] = sum(cnt[0..i)), offs[N] = E
// ---------------------------------------------------------------------------
__global__ __launch_bounds__(1024)
void scan_kernel(const int* __restrict__ cnt, int* __restrict__ offs, int N, int E) {
    __shared__ int part[1024];
    int t = threadIdx.x;
    int per = (N + 1023) >> 10;
    int beg = t * per, end = min(beg + per, N);
    int s = 0;
    for (int i = beg; i < end; ++i) s += cnt[i];
    part[t] = s;
    __syncthreads();
    for (int off = 1; off < 1024; off <<= 1) {
        int v = (t >= off) ? part[t - off] : 0;
        __syncthreads();
        part[t] += v;
        __syncthreads();
    }
    int run = (t == 0) ? 0 : part[t - 1];
    for (int i = beg; i < end; ++i) { offs[i] = run; run += cnt[i]; }
    if (t == 0) offs[N] = E;
}

// ---------------------------------------------------------------------------
// Bucket fill: sorted[offs[dst[e]] + cursor++] = src[e]
// ---------------------------------------------------------------------------
__global__ void fill_kernel(const int* __restrict__ dst, const int* __restrict__ src,
                            const int* __restrict__ offs, int* __restrict__ cur,
                            int* __restrict__ sorted, int E) {
    int e = blockIdx.x * blockDim.x + threadIdx.x;
    if (e < E) {
        int d = dst[e];
        int p = offs[d] + atomicAdd(cur + d, 1);
        sorted[p] = src[e];
    }
}

// ---------------------------------------------------------------------------
// Row split (no transpose): src[M][K] fp32 -> hi plane [M][K] u16 at dst,
// lo plane at dst + total. total = M*K (multiple of 4).
// ---------------------------------------------------------------------------
__global__ void split_rows_kernel(const float* __restrict__ src, u16* __restrict__ dst,
                                  int total) {
    int i = (blockIdx.x * 256 + threadIdx.x) * 4;
    if (i >= total) return;
    f32x4 v = *(const f32x4*)(src + i);
    us4 hv = { bhi(v.x), bhi(v.y), bhi(v.z), bhi(v.w) };
    us4 lv = { blo(v.x), blo(v.y), blo(v.z), blo(v.w) };
    *(us4*)(dst + i) = hv;
    *(us4*)(dst + (size_t)total + i) = lv;
}

// ---------------------------------------------------------------------------
// Weight pre-transpose + split: W[K][N] fp32 -> bt hi plane [N][K] bf16,
// then lo plane [N][K] bf16 at bt + N*K. Tiny (<= 262K elems).
// ---------------------------------------------------------------------------
__global__ void wsplit_kernel(const float* __restrict__ W, u16* __restrict__ bt,
                              int K, int N) {
    int idx = blockIdx.x * 256 + threadIdx.x;
    if (idx >= K * N) return;
    int k = idx / N, n = idx - k * N;          // coalesced read along n
    float v = W[idx];
    bt[(size_t)n * K + k] = bhi(v);
    bt[(size_t)N * K + (size_t)n * K + k] = blo(v);
}

// ---------------------------------------------------------------------------
// Gather-mean, D=128, plane output: one wave per dst node; lane holds
// float2 (cols 2*lane, 2*lane+1). Writes hi/lo u16 planes [Ntgt][128].
// ---------------------------------------------------------------------------
__global__ __launch_bounds__(256)
void gather_mean_128p(const float* __restrict__ x, const int* __restrict__ offs,
                      const int* __restrict__ srt, u16* __restrict__ aggP, int Ntgt) {
    int wid = (int)((blockIdx.x * 256 + threadIdx.x) >> 6);
    int lane = threadIdx.x & 63;
    if (wid >= Ntgt) return;
    int beg = offs[wid], end = offs[wid + 1];
    float ax = 0.f, ay = 0.f;
    int e = beg;
    for (; e + 8 <= end; e += 8) {
        int s0 = srt[e], s1 = srt[e + 1], s2 = srt[e + 2], s3 = srt[e + 3];
        int s4 = srt[e + 4], s5 = srt[e + 5], s6 = srt[e + 6], s7 = srt[e + 7];
        float2 v0 = ((const float2*)(x + (size_t)s0 * 128))[lane];
        float2 v1 = ((const float2*)(x + (size_t)s1 * 128))[lane];
        float2 v2 = ((const float2*)(x + (size_t)s2 * 128))[lane];
        float2 v3 = ((const float2*)(x + (size_t)s3 * 128))[lane];
        float2 v4 = ((const float2*)(x + (size_t)s4 * 128))[lane];
        float2 v5 = ((const float2*)(x + (size_t)s5 * 128))[lane];
        float2 v6 = ((const float2*)(x + (size_t)s6 * 128))[lane];
        float2 v7 = ((const float2*)(x + (size_t)s7 * 128))[lane];
        ax += v0.x + v1.x + v2.x + v3.x + v4.x + v5.x + v6.x + v7.x;
        ay += v0.y + v1.y + v2.y + v3.y + v4.y + v5.y + v6.y + v7.y;
    }
    for (; e < end; ++e) {
        int s = srt[e];
        float2 v = ((const float2*)(x + (size_t)s * 128))[lane];
        ax += v.x; ay += v.y;
    }
    float inv = 1.0f / (float)max(end - beg, 1);
    ax *= inv; ay *= inv;
    size_t stride = (size_t)Ntgt * 128;
    u32 hw = (u32)bhi(ax) | ((u32)bhi(ay) << 16);
    u32 lw = (u32)blo(ax) | ((u32)blo(ay) << 16);
    ((u32*)aggP)[(size_t)wid * 64 + lane] = hw;
    ((u32*)(aggP + stride))[(size_t)wid * 64 + lane] = lw;
}

// ---------------------------------------------------------------------------
// Gather-mean, D=512, plane output: one wave per (node, half); lane holds
// float4. Writes hi/lo u16 planes [Ntgt][512].
// ---------------------------------------------------------------------------
__global__ __launch_bounds__(256)
void gather_mean_512p(const float* __restrict__ x, const int* __restrict__ offs,
                      const int* __restrict__ srt, u16* __restrict__ aggP, int Ntgt) {
    int gw = (int)((blockIdx.x * 256 + threadIdx.x) >> 6);
    int lane = threadIdx.x & 63;
    int node = gw >> 1, half = gw & 1;
    if (node >= Ntgt) return;
    int beg = offs[node], end = offs[node + 1];
    int co = half * 256 + lane * 4;
    float4 acc = make_float4(0.f, 0.f, 0.f, 0.f);
    int e = beg;
    for (; e + 4 <= end; e += 4) {
        int s0 = srt[e], s1 = srt[e + 1], s2 = srt[e + 2], s3 = srt[e + 3];
        float4 v0 = *(const float4*)(x + (size_t)s0 * 512 + co);
        float4 v1 = *(const float4*)(x + (size_t)s1 * 512 + co);
        float4 v2 = *(const float4*)(x + (size_t)s2 * 512 + co);
        float4 v3 = *(const float4*)(x + (size_t)s3 * 512 + co);
        acc.x += v0.x + v1.x + v2.x + v3.x;
        acc.y += v0.y + v1.y + v2.y + v3.y;
        acc.z += v0.z + v1.z + v2.z + v3.z;
        acc.w += v0.w + v1.w + v2.w + v3.w;
    }
    for (; e < end; ++e) {
        int s = srt[e];
        float4 v = *(const float4*)(x + (size_t)s * 512 + co);
        acc.x += v.x; acc.y += v.y; acc.z += v.z; acc.w += v.w;
    }
    float inv = 1.0f / (float)max(end - beg, 1);
    acc.x *= inv; acc.y *= inv; acc.z *= inv; acc.w *= inv;
    size_t stride = (size_t)Ntgt * 512;
    us4 hv = { bhi(acc.x), bhi(acc.y), bhi(acc.z), bhi(acc.w) };
    us4 lv = { blo(acc.x), blo(acc.y), blo(acc.z), blo(acc.w) };
    *(us4*)(aggP + (size_t)node * 512 + co) = hv;
    *(us4*)(aggP + stride + (size_t)node * 512 + co) = lv;
}

// ---------------------------------------------------------------------------
// Fused combine via split-bf16 MFMA, pre-split-plane inputs:
//   out = act( A0 @ W0 + A1 @ W1 + bias )
// A0P/A1P: hi plane [M][K] u16 + lo plane at +M*K (pre-split by producers).
// Bt0/Bt1: pre-split weights, hi plane [N][K] + lo plane at +N*K.
// BM x 128 block tile, 256 threads = 4 waves.
//   BM=128: waves 2x2, wave tile 64x64 (NJ=4).
//   BM=64 : waves 1x4, wave tile 64x32 (NJ=2)  -- for small-M layers.
// 3 MFMA terms per fragment pair (hi*hi + hi*lo + lo*hi).
// ---------------------------------------------------------------------------
#define LDK 40   // padded k-stride in u16 (32+8): 80B rows, 16B-aligned frags

template <int BM, bool GELU>
__global__ __launch_bounds__(256)
void combine_mfma(const u16* __restrict__ A0P, const u16* __restrict__ A1P,
                  const u16* __restrict__ Bt0, const u16* __restrict__ Bt1,
                  const float* __restrict__ bias, float* __restrict__ out,
                  int M, int K, int N) {
    constexpr int NJ = (BM == 128) ? 4 : 2;     // n-frags per wave
    __shared__ u16 As_hi[BM][LDK];
    __shared__ u16 As_lo[BM][LDK];
    __shared__ u16 Bs_hi[128][LDK];
    __shared__ u16 Bs_lo[128][LDK];

    int t = threadIdx.x;
    int lane = t & 63, wid = t >> 6;
    int wm = (BM == 128) ? (wid >> 1) * 64 : 0;
    int wn = (BM == 128) ? (wid & 1) * 64 : wid * 32;
    int m0 = blockIdx.y * BM, n0 = blockIdx.x * 128;

    // staging coords: 64 rows x 32 u16 per pass; thread does 16B (8 u16)
    int sr = t >> 2;                 // row 0..63 per pass
    int sc = (t & 3) * 8;            // k oct {0,8,16,24}

    // fragment coords
    int fr = lane & 15, kg = lane >> 4;

    f32x4 acc[4][NJ] = {};

    size_t strideA = (size_t)M * K;
    size_t strideB = (size_t)N * K;

    for (int p = 0; p < 2; ++p) {
        const u16* Ah = p ? A1P : A0P;
        const u16* Al = Ah + strideA;
        const u16* Bh = p ? Bt1 : Bt0;
        const u16* Bl = Bh + strideB;

        for (int k0 = 0; k0 < K; k0 += 32) {
            // ---- stage A tile BMx32 from planes ----
#pragma unroll
            for (int it = 0; it < BM / 64; ++it) {
                int row = it * 64 + sr;
                int rg = m0 + row;
                i32x4 hv = {0, 0, 0, 0}, lv = {0, 0, 0, 0};
                if (rg < M) {
                    size_t goff = (size_t)rg * K + k0 + sc;
                    hv = *(const i32x4*)(Ah + goff);
                    lv = *(const i32x4*)(Al + goff);
                }
                *(i32x4*)&As_hi[row][sc] = hv;
                *(i32x4*)&As_lo[row][sc] = lv;
            }
            // ---- stage B tile 128n x 32k ----
#pragma unroll
            for (int it = 0; it < 2; ++it) {
                int nn = it * 64 + sr;
                size_t goff = (size_t)(n0 + nn) * K + k0 + sc;
                *(i32x4*)&Bs_hi[nn][sc] = *(const i32x4*)(Bh + goff);
                *(i32x4*)&Bs_lo[nn][sc] = *(const i32x4*)(Bl + goff);
            }
            __syncthreads();

            // ---- fragments + MFMA ----
            bf16x8 a_hi[4], a_lo[4], b_hi[NJ], b_lo[NJ];
#pragma unroll
            for (int i = 0; i < 4; ++i) {
                a_hi[i] = *(const bf16x8*)&As_hi[wm + i * 16 + fr][kg * 8];
                a_lo[i] = *(const bf16x8*)&As_lo[wm + i * 16 + fr][kg * 8];
            }
#pragma unroll
            for (int j = 0; j < NJ; ++j) {
                b_hi[j] = *(const bf16x8*)&Bs_hi[wn + j * 16 + fr][kg * 8];
                b_lo[j] = *(const bf16x8*)&Bs_lo[wn + j * 16 + fr][kg * 8];
            }
#pragma unroll
            for (int i = 0; i < 4; ++i)
#pragma unroll
                for (int j = 0; j < NJ; ++j) {
                    acc[i][j] = __builtin_amdgcn_mfma_f32_16x16x32_bf16(
                        a_hi[i], b_hi[j], acc[i][j], 0, 0, 0);
                    acc[i][j] = __builtin_amdgcn_mfma_f32_16x16x32_bf16(
                        a_hi[i], b_lo[j], acc[i][j], 0, 0, 0);
                    acc[i][j] = __builtin_amdgcn_mfma_f32_16x16x32_bf16(
                        a_lo[i], b_hi[j], acc[i][j], 0, 0, 0);
                }
            __syncthreads();
        }
    }

    // ---- epilogue: C/D layout col=lane&15, row=(lane>>4)*4+reg (m89) ----
    int fq = lane >> 4;
#pragma unroll
    for (int i = 0; i < 4; ++i) {
        int rbase = m0 + wm + i * 16 + fq * 4;
#pragma unroll
        for (int j = 0; j < NJ; ++j) {
            int c = n0 + wn + j * 16 + fr;
            float bv = bias[c];
#pragma unroll
            for (int r = 0; r < 4; ++r) {
                int row = rbase + r;
                if (row < M) {
                    float v = acc[i][j][r] + bv;
                    if (GELU) v = 0.5f * v * (1.0f + erff(v * 0.70710678118654752f));
                    out[(size_t)row * N + c] = v;
                }
            }
        }
    }
}

// ---------------------------------------------------------------------------
extern "C" void kernel_launch(void* const* d_in, const int* in_sizes, int n_in,
                              void* d_out, int out_size, void* d_ws, size_t ws_size,
                              hipStream_t stream) {
    const float* x       = (const float*)d_in[0];
    const int*   ei0_src = (const int*)d_in[1];
    const int*   ei0_dst = (const int*)d_in[2];
    const int*   ei1_src = (const int*)d_in[3];
    const int*   ei1_dst = (const int*)d_in[4];
    const int*   ei2_src = (const int*)d_in[5];
    const int*   ei2_dst = (const int*)d_in[6];
    const float* W_l0    = (const float*)d_in[7];
    const float* b_l0    = (const float*)d_in[8];
    const float* W_r0    = (const float*)d_in[9];
    const float* W_l1    = (const float*)d_in[10];
    const float* b_l1    = (const float*)d_in[11];
    const float* W_r1    = (const float*)d_in[12];
    const float* W_l2    = (const float*)d_in[13];
    const float* b_l2    = (const float*)d_in[14];
    const float* W_r2    = (const float*)d_in[15];
    float* out = (float*)d_out;
    char*  ws  = (char*)d_ws;

    // ---- workspace layout (linear, no aliasing; ~390 MB of the 2 GB ws) ----
    size_t off = 0;
    auto alloc = [&](size_t bytes) { char* p = ws + off; off += (bytes + 255) & ~(size_t)255; return p; };

    float* h1    = (float*)alloc((size_t)N1 * H * 4);        // 204.8 MB
    float* h2    = (float*)alloc((size_t)N2 * H * 4);        // 20.5 MB
    u16*   aggP0 = (u16*)alloc((size_t)N1 * D * 2 * 2);      // hi+lo planes, 51.2 MB
    u16*   xP0   = (u16*)alloc((size_t)N1 * D * 2 * 2);      // 51.2 MB
    u16*   aggP1 = (u16*)alloc((size_t)N2 * H * 2 * 2);      // 20.5 MB
    u16*   h1P   = (u16*)alloc((size_t)N2 * H * 2 * 2);      // 20.5 MB
    u16*   aggP2 = (u16*)alloc((size_t)N3 * H * 2 * 2);      // 2.1 MB
    u16*   h2P   = (u16*)alloc((size_t)N3 * H * 2 * 2);      // 2.1 MB
    u16*   bt0l  = (u16*)alloc((size_t)H * D * 2 * 2);
    u16*   bt0r  = (u16*)alloc((size_t)H * D * 2 * 2);
    u16*   bt1l  = (u16*)alloc((size_t)H * H * 2 * 2);
    u16*   bt1r  = (u16*)alloc((size_t)H * H * 2 * 2);
    u16*   bt2l  = (u16*)alloc((size_t)D * H * 2 * 2);
    u16*   bt2r  = (u16*)alloc((size_t)D * H * 2 * 2);
    int*   offs0 = (int*)alloc((size_t)(N1 + 1) * 4);
    int*   cnt0  = (int*)alloc((size_t)2 * N1 * 4);          // cnt0 + cur0 contiguous
    int*   srt0  = (int*)alloc((size_t)E0 * 4);
    int*   offs1 = (int*)alloc((size_t)(N2 + 1) * 4);
    int*   cnt1  = (int*)alloc((size_t)2 * N2 * 4);
    int*   srt1  = (int*)alloc((size_t)E1 * 4);
    int*   offs2 = (int*)alloc((size_t)(N3 + 1) * 4);
    int*   cnt2  = (int*)alloc((size_t)2 * N3 * 4);
    int*   srt2  = (int*)alloc((size_t)E2 * 4);
    int* cur0 = cnt0 + N1;
    int* cur1 = cnt1 + N2;
    int* cur2 = cnt2 + N3;

    // ---- build CSR buckets for all 3 layers ----
    hipMemsetAsync(cnt0, 0, 2 * N1 * sizeof(int), stream);
    hipMemsetAsync(cnt1, 0, 2 * N2 * sizeof(int), stream);
    hipMemsetAsync(cnt2, 0, 2 * N3 * sizeof(int), stream);
    count_kernel<<<(E0 + 255) / 256, 256, 0, stream>>>(ei0_dst, cnt0, E0);
    count_kernel<<<(E1 + 255) / 256, 256, 0, stream>>>(ei1_dst, cnt1, E1);
    count_kernel<<<(E2 + 255) / 256, 256, 0, stream>>>(ei2_dst, cnt2, E2);
    scan_kernel<<<1, 1024, 0, stream>>>(cnt0, offs0, N1, E0);
    scan_kernel<<<1, 1024, 0, stream>>>(cnt1, offs1, N2, E1);
    scan_kernel<<<1, 1024, 0, stream>>>(cnt2, offs2, N3, E2);
    fill_kernel<<<(E0 + 255) / 256, 256, 0, stream>>>(ei0_dst, ei0_src, offs0, cur0, srt0, E0);
    fill_kernel<<<(E1 + 255) / 256, 256, 0, stream>>>(ei1_dst, ei1_src, offs1, cur1, srt1, E1);
    fill_kernel<<<(E2 + 255) / 256, 256, 0, stream>>>(ei2_dst, ei2_src, offs2, cur2, srt2, E2);

    // ---- weight splits + x_tgt split (independent of CSR) ----
    wsplit_kernel<<<(D * H + 255) / 256, 256, 0, stream>>>(W_l0, bt0l, D, H);
    wsplit_kernel<<<(D * H + 255) / 256, 256, 0, stream>>>(W_r0, bt0r, D, H);
    wsplit_kernel<<<(H * H + 255) / 256, 256, 0, stream>>>(W_l1, bt1l, H, H);
    wsplit_kernel<<<(H * H + 255) / 256, 256, 0, stream>>>(W_r1, bt1r, H, H);
    wsplit_kernel<<<(H * D + 255) / 256, 256, 0, stream>>>(W_l2, bt2l, H, D);
    wsplit_kernel<<<(H * D + 255) / 256, 256, 0, stream>>>(W_r2, bt2r, H, D);
    split_rows_kernel<<<(N1 * D / 4 + 255) / 256, 256, 0, stream>>>(x, xP0, N1 * D);

    // ---- layer 0: x (N0,128) -> h1 (N1,512), GELU ----
    gather_mean_128p<<<(N1 + 3) / 4, 256, 0, stream>>>(x, offs0, srt0, aggP0, N1);
    combine_mfma<128, true><<<dim3(H / 128, (N1 + 127) / 128), 256, 0, stream>>>(
        aggP0, xP0, bt0l, bt0r, b_l0, h1, N1, D, H);

    // ---- layer 1: h1 (N1,512) -> h2 (N2,512), GELU ----
    split_rows_kernel<<<(N2 * H / 4 + 255) / 256, 256, 0, stream>>>(h1, h1P, N2 * H);
    gather_mean_512p<<<(2 * N2 + 3) / 4, 256, 0, stream>>>(h1, offs1, srt1, aggP1, N2);
    combine_mfma<64, true><<<dim3(H / 128, (N2 + 63) / 64), 256, 0, stream>>>(
        aggP1, h1P, bt1l, bt1r, b_l1, h2, N2, H, H);

    // ---- layer 2: h2 (N2,512) -> out (N3,128), no act ----
    split_rows_kernel<<<(N3 * H / 4 + 255) / 256, 256, 0, stream>>>(h2, h2P, N3 * H);
    gather_mean_512p<<<(2 * N3 + 3) / 4, 256, 0, stream>>>(h2, offs2, srt2, aggP2, N3);
    combine_mfma<64, false><<<dim3(D / 128, (N3 + 63) / 64), 256, 0, stream>>>(
        aggP2, h2P, bt2l, bt2r, b_l2, out, N3, H, D);
}

// Round 4
// 1379.232 us; speedup vs baseline: 1.3072x; 1.0390x over previous
//
#include <hip/hip_runtime.h>
#include <math.h>

// Problem constants (from reference)
static const int N0 = 1000000, N1 = 100000, N2 = 10000, N3 = 1024;
static const int E0 = 1500000, E1 = 150000, E2 = 15360;
static const int D = 128, H = 512;

typedef unsigned short u16;
typedef unsigned int u32;
typedef __attribute__((ext_vector_type(8))) short bf16x8;   // 8 bf16 = 4 VGPRs
typedef __attribute__((ext_vector_type(4))) float f32x4;
typedef __attribute__((ext_vector_type(4))) unsigned short us4;
typedef __attribute__((ext_vector_type(4))) int i32x4;

// ---------------------------------------------------------------------------
// Exact fp32 -> bf16 hi/lo split (truncation; v == hi + lo to ~2^-16 rel).
// ---------------------------------------------------------------------------
__device__ __forceinline__ u16 bhi(float v) {
    return (u16)(__float_as_uint(v) >> 16);
}
__device__ __forceinline__ u16 blo(float v) {
    float hf = __uint_as_float(__float_as_uint(v) & 0xFFFF0000u);
    return (u16)(__float_as_uint(v - hf) >> 16);
}

// ---------------------------------------------------------------------------
// Fused edge-count histogram for all 3 layers.
// ---------------------------------------------------------------------------
__global__ void count_all(const int* __restrict__ d0, const int* __restrict__ d1,
                          const int* __restrict__ d2, int* __restrict__ c0,
                          int* __restrict__ c1, int* __restrict__ c2) {
    int e = blockIdx.x * 256 + threadIdx.x;
    if (e < E0) atomicAdd(c0 + d0[e], 1);
    if (e < E1) atomicAdd(c1 + d1[e], 1);
    if (e < E2) atomicAdd(c2 + d2[e], 1);
}

// ---------------------------------------------------------------------------
// Fused exclusive scans: block b scans layer b. offs[i]=sum(cnt[0..i)), offs[N]=E.
// ---------------------------------------------------------------------------
__global__ __launch_bounds__(1024)
void scan_all(const int* __restrict__ c0, int* __restrict__ o0,
              const int* __restrict__ c1, int* __restrict__ o1,
              const int* __restrict__ c2, int* __restrict__ o2) {
    __shared__ int part[1024];
    const int* cnt; int* offs; int N, E;
    if (blockIdx.x == 0)      { cnt = c0; offs = o0; N = N1; E = E0; }
    else if (blockIdx.x == 1) { cnt = c1; offs = o1; N = N2; E = E1; }
    else                      { cnt = c2; offs = o2; N = N3; E = E2; }
    int t = threadIdx.x;
    int per = (N + 1023) >> 10;
    int beg = t * per, end = min(beg + per, N);
    int s = 0;
    for (int i = beg; i < end; ++i) s += cnt[i];
    part[t] = s;
    __syncthreads();
    for (int off = 1; off < 1024; off <<= 1) {
        int v = (t >= off) ? part[t - off] : 0;
        __syncthreads();
        part[t] += v;
        __syncthreads();
    }
    int run = (t == 0) ? 0 : part[t - 1];
    for (int i = beg; i < end; ++i) { offs[i] = run; run += cnt[i]; }
    if (t == 0) offs[N] = E;
}

// ---------------------------------------------------------------------------
// Fused bucket fill for all 3 layers: sorted[offs[dst[e]] + cursor++] = src[e]
// ---------------------------------------------------------------------------
__global__ void fill_all(const int* __restrict__ d0, const int* __restrict__ s0,
                         const int* __restrict__ of0, int* __restrict__ cu0, int* __restrict__ sr0,
                         const int* __restrict__ d1, const int* __restrict__ s1,
                         const int* __restrict__ of1, int* __restrict__ cu1, int* __restrict__ sr1,
                         const int* __restrict__ d2, const int* __restrict__ s2,
                         const int* __restrict__ of2, int* __restrict__ cu2, int* __restrict__ sr2) {
    int e = blockIdx.x * 256 + threadIdx.x;
    if (e < E0) { int d = d0[e]; sr0[of0[d] + atomicAdd(cu0 + d, 1)] = s0[e]; }
    if (e < E1) { int d = d1[e]; sr1[of1[d] + atomicAdd(cu1 + d, 1)] = s1[e]; }
    if (e < E2) { int d = d2[e]; sr2[of2[d] + atomicAdd(cu2 + d, 1)] = s2[e]; }
}

// ---------------------------------------------------------------------------
// Fused weight pre-transpose + split for all 6 matrices.
// W[K][N] fp32 -> hi plane [N][K] bf16, lo plane at +N*K.
// ---------------------------------------------------------------------------
__device__ __forceinline__ void wsplit1(const float* W, u16* bt, int idx, int K, int N) {
    int k = idx / N, n = idx - k * N;
    float v = W[idx];
    bt[(size_t)n * K + k] = bhi(v);
    bt[(size_t)N * K + (size_t)n * K + k] = blo(v);
}
__global__ void wsplit_all(const float* __restrict__ Wl0, u16* __restrict__ b0l,
                           const float* __restrict__ Wr0, u16* __restrict__ b0r,
                           const float* __restrict__ Wl1, u16* __restrict__ b1l,
                           const float* __restrict__ Wr1, u16* __restrict__ b1r,
                           const float* __restrict__ Wl2, u16* __restrict__ b2l,
                           const float* __restrict__ Wr2, u16* __restrict__ b2r) {
    const int S0 = D * H;        // 65536
    const int S1 = H * H;        // 262144
    int idx = blockIdx.x * 256 + threadIdx.x;
    if (idx < S0)                 { wsplit1(Wl0, b0l, idx, D, H); return; }
    idx -= S0;
    if (idx < S0)                 { wsplit1(Wr0, b0r, idx, D, H); return; }
    idx -= S0;
    if (idx < S1)                 { wsplit1(Wl1, b1l, idx, H, H); return; }
    idx -= S1;
    if (idx < S1)                 { wsplit1(Wr1, b1r, idx, H, H); return; }
    idx -= S1;
    if (idx < S0)                 { wsplit1(Wl2, b2l, idx, H, D); return; }
    idx -= S0;
    if (idx < S0)                 { wsplit1(Wr2, b2r, idx, H, D); return; }
}

// ---------------------------------------------------------------------------
// Row split (no transpose): src[M][K] fp32 -> hi plane [M][K] u16 at dst,
// lo plane at dst + total. total = M*K (multiple of 4).
// ---------------------------------------------------------------------------
__global__ void split_rows_kernel(const float* __restrict__ src, u16* __restrict__ dst,
                                  int total) {
    int i = (blockIdx.x * 256 + threadIdx.x) * 4;
    if (i >= total) return;
    f32x4 v = *(const f32x4*)(src + i);
    us4 hv = { bhi(v.x), bhi(v.y), bhi(v.z), bhi(v.w) };
    us4 lv = { blo(v.x), blo(v.y), blo(v.z), blo(v.w) };
    *(us4*)(dst + i) = hv;
    *(us4*)(dst + (size_t)total + i) = lv;
}

// ---------------------------------------------------------------------------
// Gather-mean, D=128, plane output: one wave per dst node; lane holds
// float2 (cols 2*lane, 2*lane+1). Writes hi/lo u16 planes [Ntgt][128].
// ---------------------------------------------------------------------------
__global__ __launch_bounds__(256)
void gather_mean_128p(const float* __restrict__ x, const int* __restrict__ offs,
                      const int* __restrict__ srt, u16* __restrict__ aggP, int Ntgt) {
    int wid = (int)((blockIdx.x * 256 + threadIdx.x) >> 6);
    int lane = threadIdx.x & 63;
    if (wid >= Ntgt) return;
    int beg = offs[wid], end = offs[wid + 1];
    float ax = 0.f, ay = 0.f;
    int e = beg;
    for (; e + 8 <= end; e += 8) {
        int s0 = srt[e], s1 = srt[e + 1], s2 = srt[e + 2], s3 = srt[e + 3];
        int s4 = srt[e + 4], s5 = srt[e + 5], s6 = srt[e + 6], s7 = srt[e + 7];
        float2 v0 = ((const float2*)(x + (size_t)s0 * 128))[lane];
        float2 v1 = ((const float2*)(x + (size_t)s1 * 128))[lane];
        float2 v2 = ((const float2*)(x + (size_t)s2 * 128))[lane];
        float2 v3 = ((const float2*)(x + (size_t)s3 * 128))[lane];
        float2 v4 = ((const float2*)(x + (size_t)s4 * 128))[lane];
        float2 v5 = ((const float2*)(x + (size_t)s5 * 128))[lane];
        float2 v6 = ((const float2*)(x + (size_t)s6 * 128))[lane];
        float2 v7 = ((const float2*)(x + (size_t)s7 * 128))[lane];
        ax += v0.x + v1.x + v2.x + v3.x + v4.x + v5.x + v6.x + v7.x;
        ay += v0.y + v1.y + v2.y + v3.y + v4.y + v5.y + v6.y + v7.y;
    }
    for (; e < end; ++e) {
        int s = srt[e];
        float2 v = ((const float2*)(x + (size_t)s * 128))[lane];
        ax += v.x; ay += v.y;
    }
    float inv = 1.0f / (float)max(end - beg, 1);
    ax *= inv; ay *= inv;
    size_t stride = (size_t)Ntgt * 128;
    u32 hw = (u32)bhi(ax) | ((u32)bhi(ay) << 16);
    u32 lw = (u32)blo(ax) | ((u32)blo(ay) << 16);
    ((u32*)aggP)[(size_t)wid * 64 + lane] = hw;
    ((u32*)(aggP + stride))[(size_t)wid * 64 + lane] = lw;
}

// ---------------------------------------------------------------------------
// Gather-mean, D=512, plane output: one wave per (node, half); lane holds
// float4. Writes hi/lo u16 planes [Ntgt][512].
// ---------------------------------------------------------------------------
__global__ __launch_bounds__(256)
void gather_mean_512p(const float* __restrict__ x, const int* __restrict__ offs,
                      const int* __restrict__ srt, u16* __restrict__ aggP, int Ntgt) {
    int gw = (int)((blockIdx.x * 256 + threadIdx.x) >> 6);
    int lane = threadIdx.x & 63;
    int node = gw >> 1, half = gw & 1;
    if (node >= Ntgt) return;
    int beg = offs[node], end = offs[node + 1];
    int co = half * 256 + lane * 4;
    float4 acc = make_float4(0.f, 0.f, 0.f, 0.f);
    int e = beg;
    for (; e + 8 <= end; e += 8) {
        int s0 = srt[e], s1 = srt[e + 1], s2 = srt[e + 2], s3 = srt[e + 3];
        int s4 = srt[e + 4], s5 = srt[e + 5], s6 = srt[e + 6], s7 = srt[e + 7];
        float4 v0 = *(const float4*)(x + (size_t)s0 * 512 + co);
        float4 v1 = *(const float4*)(x + (size_t)s1 * 512 + co);
        float4 v2 = *(const float4*)(x + (size_t)s2 * 512 + co);
        float4 v3 = *(const float4*)(x + (size_t)s3 * 512 + co);
        float4 v4 = *(const float4*)(x + (size_t)s4 * 512 + co);
        float4 v5 = *(const float4*)(x + (size_t)s5 * 512 + co);
        float4 v6 = *(const float4*)(x + (size_t)s6 * 512 + co);
        float4 v7 = *(const float4*)(x + (size_t)s7 * 512 + co);
        acc.x += v0.x + v1.x + v2.x + v3.x + v4.x + v5.x + v6.x + v7.x;
        acc.y += v0.y + v1.y + v2.y + v3.y + v4.y + v5.y + v6.y + v7.y;
        acc.z += v0.z + v1.z + v2.z + v3.z + v4.z + v5.z + v6.z + v7.z;
        acc.w += v0.w + v1.w + v2.w + v3.w + v4.w + v5.w + v6.w + v7.w;
    }
    for (; e < end; ++e) {
        int s = srt[e];
        float4 v = *(const float4*)(x + (size_t)s * 512 + co);
        acc.x += v.x; acc.y += v.y; acc.z += v.z; acc.w += v.w;
    }
    float inv = 1.0f / (float)max(end - beg, 1);
    acc.x *= inv; acc.y *= inv; acc.z *= inv; acc.w *= inv;
    size_t stride = (size_t)Ntgt * 512;
    us4 hv = { bhi(acc.x), bhi(acc.y), bhi(acc.z), bhi(acc.w) };
    us4 lv = { blo(acc.x), blo(acc.y), blo(acc.z), blo(acc.w) };
    *(us4*)(aggP + (size_t)node * 512 + co) = hv;
    *(us4*)(aggP + stride + (size_t)node * 512 + co) = lv;
}

// ---------------------------------------------------------------------------
// Fused combine via split-bf16 MFMA, pre-split-plane inputs:
//   out = act( A0 @ W0 + A1 @ W1 + bias )
// A0P/A1P: hi plane [M][K] u16 + lo plane at +M*K.
// Bt0/Bt1: pre-split weights, hi plane [N][K] + lo plane at +N*K.
// BM x 128 block tile, 256 threads = 4 waves.
//   BM=128: waves 2x2, wave tile 64x64 (NJ=4).
//   BM=64 : waves 1x4, wave tile 64x32 (NJ=2).
// NX = N/128 grid columns. For NX==4 an XCD-chunked swizzle places all 4
// n-tiles of one m-tile on the SAME XCD within a 32-block dispatch window
// (bijective: L = 32*(m>>3) + 8*n + (m&7)) so A re-reads hit that XCD's L2.
// If PLANES: epilogue also writes hi/lo split planes of out rows < MP
// (outP hi at [r][c], lo at +MP*N) -- feeds the next layer's x_tgt operand.
// 3 MFMA terms per fragment pair (hi*hi + hi*lo + lo*hi).
// ---------------------------------------------------------------------------
#define LDK 40   // padded k-stride in u16 (32+8): 80B rows, 16B-aligned frags

template <int BM, int NX, bool GELU, bool PLANES>
__global__ __launch_bounds__(256)
void combine_mfma(const u16* __restrict__ A0P, const u16* __restrict__ A1P,
                  const u16* __restrict__ Bt0, const u16* __restrict__ Bt1,
                  const float* __restrict__ bias, float* __restrict__ out,
                  u16* __restrict__ outP, int MP,
                  int M, int K, int N) {
    constexpr int NJ = (BM == 128) ? 4 : 2;     // n-frags per wave
    __shared__ u16 As_hi[BM][LDK];
    __shared__ u16 As_lo[BM][LDK];
    __shared__ u16 Bs_hi[128][LDK];
    __shared__ u16 Bs_lo[128][LDK];

    // --- XCD-chunked block swizzle (bijective when grid = NX * (Mt mult 8)) ---
    int L = blockIdx.x;
    int m_t, n_t;
    if (NX == 4) { n_t = (L >> 3) & 3; m_t = (L & 7) + ((L >> 5) << 3); }
    else         { n_t = L % NX;       m_t = L / NX; }
    int m0 = m_t * BM, n0 = n_t * 128;
    if (m0 >= M) return;

    int t = threadIdx.x;
    int lane = t & 63, wid = t >> 6;
    int wm = (BM == 128) ? (wid >> 1) * 64 : 0;
    int wn = (BM == 128) ? (wid & 1) * 64 : wid * 32;

    // staging coords: 64 rows x 32 u16 per pass; thread does 16B (8 u16)
    int sr = t >> 2;                 // row 0..63 per pass
    int sc = (t & 3) * 8;            // k oct {0,8,16,24}

    // fragment coords
    int fr = lane & 15, kg = lane >> 4;

    f32x4 acc[4][NJ] = {};

    size_t strideA = (size_t)M * K;
    size_t strideB = (size_t)N * K;

    for (int p = 0; p < 2; ++p) {
        const u16* Ah = p ? A1P : A0P;
        const u16* Al = Ah + strideA;
        const u16* Bh = p ? Bt1 : Bt0;
        const u16* Bl = Bh + strideB;

        for (int k0 = 0; k0 < K; k0 += 32) {
            // ---- stage A tile BMx32 from planes ----
#pragma unroll
            for (int it = 0; it < BM / 64; ++it) {
                int row = it * 64 + sr;
                int rg = m0 + row;
                i32x4 hv = {0, 0, 0, 0}, lv = {0, 0, 0, 0};
                if (rg < M) {
                    size_t goff = (size_t)rg * K + k0 + sc;
                    hv = *(const i32x4*)(Ah + goff);
                    lv = *(const i32x4*)(Al + goff);
                }
                *(i32x4*)&As_hi[row][sc] = hv;
                *(i32x4*)&As_lo[row][sc] = lv;
            }
            // ---- stage B tile 128n x 32k ----
#pragma unroll
            for (int it = 0; it < 2; ++it) {
                int nn = it * 64 + sr;
                size_t goff = (size_t)(n0 + nn) * K + k0 + sc;
                *(i32x4*)&Bs_hi[nn][sc] = *(const i32x4*)(Bh + goff);
                *(i32x4*)&Bs_lo[nn][sc] = *(const i32x4*)(Bl + goff);
            }
            __syncthreads();

            // ---- fragments + MFMA ----
            bf16x8 a_hi[4], a_lo[4], b_hi[NJ], b_lo[NJ];
#pragma unroll
            for (int i = 0; i < 4; ++i) {
                a_hi[i] = *(const bf16x8*)&As_hi[wm + i * 16 + fr][kg * 8];
                a_lo[i] = *(const bf16x8*)&As_lo[wm + i * 16 + fr][kg * 8];
            }
#pragma unroll
            for (int j = 0; j < NJ; ++j) {
                b_hi[j] = *(const bf16x8*)&Bs_hi[wn + j * 16 + fr][kg * 8];
                b_lo[j] = *(const bf16x8*)&Bs_lo[wn + j * 16 + fr][kg * 8];
            }
#pragma unroll
            for (int i = 0; i < 4; ++i)
#pragma unroll
                for (int j = 0; j < NJ; ++j) {
                    acc[i][j] = __builtin_amdgcn_mfma_f32_16x16x32_bf16(
                        a_hi[i], b_hi[j], acc[i][j], 0, 0, 0);
                    acc[i][j] = __builtin_amdgcn_mfma_f32_16x16x32_bf16(
                        a_hi[i], b_lo[j], acc[i][j], 0, 0, 0);
                    acc[i][j] = __builtin_amdgcn_mfma_f32_16x16x32_bf16(
                        a_lo[i], b_hi[j], acc[i][j], 0, 0, 0);
                }
            __syncthreads();
        }
    }

    // ---- epilogue: C/D layout col=lane&15, row=(lane>>4)*4+reg (m89) ----
    int fq = lane >> 4;
#pragma unroll
    for (int i = 0; i < 4; ++i) {
        int rbase = m0 + wm + i * 16 + fq * 4;
#pragma unroll
        for (int j = 0; j < NJ; ++j) {
            int c = n0 + wn + j * 16 + fr;
            float bv = bias[c];
#pragma unroll
            for (int r = 0; r < 4; ++r) {
                int row = rbase + r;
                if (row < M) {
                    float v = acc[i][j][r] + bv;
                    if (GELU) v = 0.5f * v * (1.0f + erff(v * 0.70710678118654752f));
                    out[(size_t)row * N + c] = v;
                    if (PLANES && row < MP) {
                        size_t po = (size_t)row * N + c;
                        outP[po] = bhi(v);
                        outP[(size_t)MP * N + po] = blo(v);
                    }
                }
            }
        }
    }
}

// ---------------------------------------------------------------------------
extern "C" void kernel_launch(void* const* d_in, const int* in_sizes, int n_in,
                              void* d_out, int out_size, void* d_ws, size_t ws_size,
                              hipStream_t stream) {
    const float* x       = (const float*)d_in[0];
    const int*   ei0_src = (const int*)d_in[1];
    const int*   ei0_dst = (const int*)d_in[2];
    const int*   ei1_src = (const int*)d_in[3];
    const int*   ei1_dst = (const int*)d_in[4];
    const int*   ei2_src = (const int*)d_in[5];
    const int*   ei2_dst = (const int*)d_in[6];
    const float* W_l0    = (const float*)d_in[7];
    const float* b_l0    = (const float*)d_in[8];
    const float* W_r0    = (const float*)d_in[9];
    const float* W_l1    = (const float*)d_in[10];
    const float* b_l1    = (const float*)d_in[11];
    const float* W_r1    = (const float*)d_in[12];
    const float* W_l2    = (const float*)d_in[13];
    const float* b_l2    = (const float*)d_in[14];
    const float* W_r2    = (const float*)d_in[15];
    float* out = (float*)d_out;
    char*  ws  = (char*)d_ws;

    // ---- workspace layout (linear, no aliasing; ~390 MB of the 2 GB ws) ----
    size_t off = 0;
    auto alloc = [&](size_t bytes) { char* p = ws + off; off += (bytes + 255) & ~(size_t)255; return p; };

    float* h1    = (float*)alloc((size_t)N1 * H * 4);        // 204.8 MB
    float* h2    = (float*)alloc((size_t)N2 * H * 4);        // 20.5 MB
    u16*   aggP0 = (u16*)alloc((size_t)N1 * D * 2 * 2);      // hi+lo planes
    u16*   xP0   = (u16*)alloc((size_t)N1 * D * 2 * 2);
    u16*   aggP1 = (u16*)alloc((size_t)N2 * H * 2 * 2);
    u16*   h1P   = (u16*)alloc((size_t)N2 * H * 2 * 2);
    u16*   aggP2 = (u16*)alloc((size_t)N3 * H * 2 * 2);
    u16*   h2P   = (u16*)alloc((size_t)N3 * H * 2 * 2);
    u16*   bt0l  = (u16*)alloc((size_t)H * D * 2 * 2);
    u16*   bt0r  = (u16*)alloc((size_t)H * D * 2 * 2);
    u16*   bt1l  = (u16*)alloc((size_t)H * H * 2 * 2);
    u16*   bt1r  = (u16*)alloc((size_t)H * H * 2 * 2);
    u16*   bt2l  = (u16*)alloc((size_t)D * H * 2 * 2);
    u16*   bt2r  = (u16*)alloc((size_t)D * H * 2 * 2);
    int*   offs0 = (int*)alloc((size_t)(N1 + 1) * 4);
    int*   offs1 = (int*)alloc((size_t)(N2 + 1) * 4);
    int*   offs2 = (int*)alloc((size_t)(N3 + 1) * 4);
    int*   cntAll = (int*)alloc((size_t)2 * (N1 + N2 + N3) * 4);   // one memset
    int*   srt0  = (int*)alloc((size_t)E0 * 4);
    int*   srt1  = (int*)alloc((size_t)E1 * 4);
    int*   srt2  = (int*)alloc((size_t)E2 * 4);
    int* cnt0 = cntAll;          int* cur0 = cnt0 + N1;
    int* cnt1 = cur0 + N1;       int* cur1 = cnt1 + N2;
    int* cnt2 = cur1 + N2;       int* cur2 = cnt2 + N3;

    // ---- build CSR buckets for all 3 layers (4 launches total) ----
    hipMemsetAsync(cntAll, 0, 2 * (N1 + N2 + N3) * sizeof(int), stream);
    count_all<<<(E0 + 255) / 256, 256, 0, stream>>>(ei0_dst, ei1_dst, ei2_dst, cnt0, cnt1, cnt2);
    scan_all<<<3, 1024, 0, stream>>>(cnt0, offs0, cnt1, offs1, cnt2, offs2);
    fill_all<<<(E0 + 255) / 256, 256, 0, stream>>>(
        ei0_dst, ei0_src, offs0, cur0, srt0,
        ei1_dst, ei1_src, offs1, cur1, srt1,
        ei2_dst, ei2_src, offs2, cur2, srt2);

    // ---- weight splits (1 launch) + x_tgt split ----
    wsplit_all<<<(2 * D * H + 2 * H * H + 2 * H * D + 255) / 256, 256, 0, stream>>>(
        W_l0, bt0l, W_r0, bt0r, W_l1, bt1l, W_r1, bt1r, W_l2, bt2l, W_r2, bt2r);
    split_rows_kernel<<<(N1 * D / 4 + 255) / 256, 256, 0, stream>>>(x, xP0, N1 * D);

    // ---- layer 0: x (N0,128) -> h1 (N1,512), GELU; epilogue splits h1[:N2] ----
    gather_mean_128p<<<(N1 + 3) / 4, 256, 0, stream>>>(x, offs0, srt0, aggP0, N1);
    {
        int Mt = (N1 + 127) / 128;           // 782
        int MtPad = (Mt + 7) & ~7;           // 784
        combine_mfma<128, 4, true, true><<<4 * MtPad, 256, 0, stream>>>(
            aggP0, xP0, bt0l, bt0r, b_l0, h1, h1P, N2, N1, D, H);
    }

    // ---- layer 1: h1 (N1,512) -> h2 (N2,512), GELU; epilogue splits h2[:N3] ----
    gather_mean_512p<<<(2 * N2 + 3) / 4, 256, 0, stream>>>(h1, offs1, srt1, aggP1, N2);
    {
        int Mt = (N2 + 63) / 64;             // 157
        int MtPad = (Mt + 7) & ~7;           // 160
        combine_mfma<64, 4, true, true><<<4 * MtPad, 256, 0, stream>>>(
            aggP1, h1P, bt1l, bt1r, b_l1, h2, h2P, N3, N2, H, H);
    }

    // ---- layer 2: h2 (N2,512) -> out (N3,128), no act ----
    gather_mean_512p<<<(2 * N3 + 3) / 4, 256, 0, stream>>>(h2, offs2, srt2, aggP2, N3);
    {
        int Mt = (N3 + 63) / 64;             // 16
        combine_mfma<64, 1, false, false><<<1 * Mt, 256, 0, stream>>>(
            aggP2, h2P, bt2l, bt2r, b_l2, out, (u16*)nullptr, 0, N3, H, D);
    }
}